// Round 7
// baseline (1079.150 us; speedup 1.0000x reference)
//
#include <hip/hip_runtime.h>
#include <math.h>

namespace {
constexpr int D     = 192;
constexpr int HW    = 256 * 512;   // 131072 = 2^17
constexpr int TOTAL = 2 * HW;      // 262144 pixels

// Correctly-rounded s/5 in 3 ops (Markstein): bit-exact vs IEEE s/5.0f for
// all normal s >= 0 (our s in [0,5)).
__device__ __forceinline__ float div5(float s) {
    const float c = 0.2f;
    float q = s * c;
    float r = __builtin_fmaf(-5.0f, q, s);
    return __builtin_fmaf(r, c, q);
}

// Value-identity that the optimizer cannot see through: blocks cross-pass CSE
// of the blur chain (which would otherwise demand +192 live regs and spill).
__device__ __forceinline__ float opaque(float v) {
    asm("" : "+v"(v));
    return v;
}

__device__ __forceinline__ bool in_range(int d, int lo, unsigned width) {
    return (unsigned)(d - lo) <= width;
}

// Streaming modal-mask state machine, bit-exact vs the numpy reference.
struct Machine {
    float bprev, maxv;
    int   index, last_fall, index_l, index_r;
    bool  r_found;

    __device__ __forceinline__ void init() {
        bprev = 1.0f;          // "ones" prepend: diff at d=0 is b0 - 1 < 0 -> fall
        maxv  = -INFINITY;
        index = 0; last_fall = 0; index_l = 0;
        index_r = D - 1;       // default: rise at virtual position D (append ones)
        r_found = false;
    }

    __device__ __forceinline__ void step(int d, float b) {
        float diff = b - bprev;
        bool fall  = diff < 0.0f;
        last_fall  = fall ? d : last_fall;               // strict fall
        bool am    = b > maxv;                           // first-occurrence argmax
        maxv       = am ? b : maxv;
        index      = am ? d : index;
        index_l    = am ? last_fall : index_l;           // last fall <= new argmax
        bool rise  = (diff > 0.0f) & (!r_found) & (!am); // first strict rise AFTER argmax
        index_r    = am ? (D - 1) : (rise ? (d - 1) : index_r);
        r_found    = am ? false : (r_found | rise);
        bprev      = b;
    }

    __device__ __forceinline__ void finish(int& lo, unsigned& wd) const {
        int r = min(index_r - index, index - index_l);
        int t = 2 * index - index_r - index_l;
        bool valid = (t > -3) && (t < 3);
        lo = valid ? index_l : (index - r);
        int hi = valid ? index_r : (index + r);
        wd = (unsigned)(hi - lo);
    }
};
} // namespace

extern "C" __global__ void __launch_bounds__(256, 2)
dme_kernel(const float* __restrict__ x, float* __restrict__ out)
{
    // n is block-uniform: 512 blocks per image -> base pointer lives in SGPRs.
    const int n  = blockIdx.x >> 9;
    const int hw = ((blockIdx.x & 511) << 8) | threadIdx.x;
    const float* __restrict__ col = x + (size_t)n * (size_t)(D * HW) + hw;

    // ---- single memory pass: the whole column lives in registers ----
    // All 192 loads are mutually independent; the compiler schedules them
    // ahead of / interleaved with pass-1 compute with fine-grained vmcnt.
    float xv[D];
    #pragma unroll
    for (int d = 0; d < D; ++d) xv[d] = col[(size_t)d * HW];

    // ================= pass 1: modal mask of blur(x) =================
    Machine m1; m1.init();
    #pragma unroll
    for (int d = 0; d < D; ++d) {
        // exact left-to-right window sum, matching reference add order:
        // ((((x[d-2]+x[d-1])+x[d])+x[d+1])+x[d+2]) with zero padding
        float s = (d >= 2 ? xv[d - 2] : 0.0f) + (d >= 1 ? xv[d - 1] : 0.0f);
        s += xv[d];
        s += (d + 1 < D ? xv[d + 1] : 0.0f);
        s += (d + 2 < D ? xv[d + 2] : 0.0f);
        m1.step(d, div5(s));
    }
    int lo1; unsigned wd1; m1.finish(lo1, wd1);

    // ====== pass 2 (register-only): modal mask of blur(x)*~mask1 ======
    Machine m2; m2.init();
    #pragma unroll
    for (int d = 0; d < D; ++d) {
        // opaque() on the first operand makes this chain non-CSE-able with
        // pass 1 (recompute is 7 ops from regs; caching would cost 192 regs).
        float s = opaque(d >= 2 ? xv[d - 2] : 0.0f) + (d >= 1 ? xv[d - 1] : 0.0f);
        s += xv[d];
        s += (d + 1 < D ? xv[d + 1] : 0.0f);
        s += (d + 2 < D ? xv[d + 2] : 0.0f);
        float b = div5(s);
        bool in1 = in_range(d, lo1, wd1);
        m2.step(d, in1 ? 0.0f : b);              // x_blur2 = x_blur * ~mask1
    }
    int lo2; unsigned wd2; m2.finish(lo2, wd2);

    // ====== pass 3 (register-only): y-sums and z-sums, ascending d ======
    // y = x*mask1 ; z = x*mask2nd*~mask1. Same fold order as the reference.
    float sum_y = 0.f, wsum_y = 0.f, sum_z = 0.f, wsum_z = 0.f;
    #pragma unroll
    for (int d = 0; d < D; ++d) {
        bool in1 = in_range(d, lo1, wd1);
        bool zin = in_range(d, lo2, wd2) & !in1;
        float ty = in1 ? xv[d] : 0.0f;
        float tz = zin ? xv[d] : 0.0f;
        sum_y += ty;
        wsum_y = __builtin_fmaf((float)d, ty, wsum_y);   // fma(d,0,w)==w exactly
        sum_z += tz;
        wsum_z = __builtin_fmaf((float)d, tz, wsum_z);
    }

    bool  v = (sum_y >= sum_z);
    float S = v ? sum_y  : sum_z;
    float W = v ? wsum_y : wsum_z;
    out[hw + n * HW] = W / S;    // == sum(xm*d)/sum(xm)
}

extern "C" void kernel_launch(void* const* d_in, const int* in_sizes, int n_in,
                              void* d_out, int out_size, void* d_ws, size_t ws_size,
                              hipStream_t stream)
{
    const float* x   = (const float*)d_in[0];
    float*       out = (float*)d_out;
    dim3 block(256), grid(TOTAL / 256);          // 1024 blocks
    hipLaunchKernelGGL(dme_kernel, grid, block, 0, stream, x, out);
}